// Round 14
// baseline (3267.004 us; speedup 1.0000x reference)
//
#include <hip/hip_runtime.h>
#include <hip/hip_bf16.h>
#include <math.h>

#define BB 16
#define TT 12
#define NN 1024
#define FF 8
#define HH 64
#define EE 32768
#define DIN 320   // H * (2K+1)
#define ODIM 96   // F * HORIZON
#define FS 512    // feats cols: [Af|Af2|Ab|Ab2] x [x(64)|h(64)]
#define APAD 40   // k_msq LDS row stride

typedef short v8s __attribute__((ext_vector_type(8)));
typedef float v4f __attribute__((ext_vector_type(4)));

__device__ __forceinline__ unsigned short f2bf_rne(float v) {
    unsigned u = __float_as_uint(v);
    u += 0x7FFF + ((u >> 16) & 1);
    return (unsigned short)(u >> 16);
}
__device__ __forceinline__ float bfu2f(unsigned short u) {
    return __uint_as_float((unsigned)u << 16);
}
__device__ __forceinline__ void split_bf(float v, unsigned short& hi, unsigned short& lo) {
    hi = f2bf_rne(v);
    lo = f2bf_rne(v - bfu2f(hi));
}

// ---------------- edge_index insurance ----------------
__global__ void k_ei_detect(const int* __restrict__ ei_raw, int* __restrict__ flag) {
    __shared__ int s[256];
    s[threadIdx.x] = ei_raw[2 * threadIdx.x + 1];
    __syncthreads();
    for (int st = 128; st > 0; st >>= 1) {
        if (threadIdx.x < st) s[threadIdx.x] |= s[threadIdx.x + st];
        __syncthreads();
    }
    if (threadIdx.x == 0) flag[0] = (s[0] == 0) ? 1 : 0;
}
__global__ void k_ei_norm(const int* __restrict__ ei_raw, const int* __restrict__ flag,
                          int* __restrict__ ei32) {
    int j = blockIdx.x * 256 + threadIdx.x;
    ei32[j] = flag[0] ? ei_raw[2 * j] : ei_raw[j];
}

// ---------------- support normalization ----------------
__global__ void k_rowsum(const float* __restrict__ adj, float* __restrict__ rinv) {
    __shared__ float s[256];
    int i = blockIdx.x;
    float acc = 0.f;
    for (int j = threadIdx.x; j < NN; j += 256) acc += adj[i * NN + j];
    s[threadIdx.x] = acc;
    __syncthreads();
    for (int st = 128; st > 0; st >>= 1) {
        if (threadIdx.x < st) s[threadIdx.x] += s[threadIdx.x + st];
        __syncthreads();
    }
    if (threadIdx.x == 0) rinv[i] = (s[0] != 0.f) ? 1.f / s[0] : 0.f;
}
__global__ void k_colsum(const float* __restrict__ adj, float* __restrict__ cinv) {
    int j = blockIdx.x * 256 + threadIdx.x;
    float acc = 0.f;
    for (int i = 0; i < NN; i++) acc += adj[i * NN + j];
    cinv[j] = (acc != 0.f) ? 1.f / acc : 0.f;
}

// ---------------- Af -> plain rows 0..1023, Ab -> plain rows 2048..3071 (split bf16) ----------------
__global__ __launch_bounds__(256) void k_prepA(
        const float* __restrict__ adj, const float* __restrict__ rinv,
        const float* __restrict__ cinv,
        unsigned short* __restrict__ Mh, unsigned short* __restrict__ Ml) {
    int w0 = blockIdx.x * 64, v0 = blockIdx.y * 64;
    __shared__ float T[64][68];
    int row = threadIdx.x >> 2, cs = (threadIdx.x & 3) * 16;
    #pragma unroll
    for (int j = 0; j < 4; j++)
        *(float4*)&T[row][cs + j * 4] = *(const float4*)(adj + (size_t)(w0 + row) * NN + v0 + cs + j * 4);
    __syncthreads();
    {
        float sc = rinv[w0 + row];
        unsigned short h8[16], l8[16];
        #pragma unroll
        for (int j = 0; j < 16; j++) split_bf(T[row][cs + j] * sc, h8[j], l8[j]);
        size_t ofs = (size_t)(w0 + row) * NN + v0 + cs;
        ((uint4*)(Mh + ofs))[0] = *(uint4*)&h8[0];
        ((uint4*)(Mh + ofs))[1] = *(uint4*)&h8[8];
        ((uint4*)(Ml + ofs))[0] = *(uint4*)&l8[0];
        ((uint4*)(Ml + ofs))[1] = *(uint4*)&l8[8];
    }
    {
        float sc = cinv[v0 + row];
        unsigned short h8[16], l8[16];
        #pragma unroll
        for (int j = 0; j < 16; j++) split_bf(T[cs + j][row] * sc, h8[j], l8[j]);
        size_t ofs = (size_t)2048 * NN + (size_t)(v0 + row) * NN + w0 + cs;
        ((uint4*)(Mh + ofs))[0] = *(uint4*)&h8[0];
        ((uint4*)(Mh + ofs))[1] = *(uint4*)&h8[8];
        ((uint4*)(Ml + ofs))[0] = *(uint4*)&l8[0];
        ((uint4*)(Ml + ofs))[1] = *(uint4*)&l8[8];
    }
}

// ---------------- plain M rows (zz) squared: rows zz*2048 -> zz*2048+1024 ----------------
__global__ __launch_bounds__(256) void k_msq(
        unsigned short* __restrict__ Mh, unsigned short* __restrict__ Ml) {
    int zz = blockIdx.z;
    size_t srcb = (size_t)zz * 2048 * NN;
    size_t dstb = srcb + (size_t)1024 * NN;
    int w0 = blockIdx.x * 64, n0 = blockIdx.y * 64;

    __shared__ unsigned short sAh[64 * APAD];
    __shared__ unsigned short sAl[64 * APAD];
    __shared__ unsigned short sBh[64 * APAD];
    __shared__ unsigned short sBl[64 * APAD];

    int tid = threadIdx.x;
    int lane = tid & 63, wave = tid >> 6;
    int wr = (wave >> 1) * 32, wc = (wave & 1) * 32;
    int l15 = lane & 15, quad = lane >> 4;
    int arow = tid >> 2, akk = (tid & 3) * 8;
    int bkr = tid & 31, bc8 = (tid >> 5) * 8;

    v4f acc[2][2];
    #pragma unroll
    for (int i = 0; i < 2; i++)
        #pragma unroll
        for (int j = 0; j < 2; j++) { acc[i][j][0]=0.f; acc[i][j][1]=0.f; acc[i][j][2]=0.f; acc[i][j][3]=0.f; }

    for (int k0 = 0; k0 < NN; k0 += 32) {
        size_t aofs = srcb + (size_t)(w0 + arow) * NN + k0 + akk;
        *(uint4*)&sAh[arow * APAD + akk] = *(const uint4*)(Mh + aofs);
        *(uint4*)&sAl[arow * APAD + akk] = *(const uint4*)(Ml + aofs);
        size_t bofs = srcb + (size_t)(k0 + bkr) * NN + n0 + bc8;
        uint4 bh = *(const uint4*)(Mh + bofs);
        uint4 bl = *(const uint4*)(Ml + bofs);
        const unsigned short* ph = (const unsigned short*)&bh;
        const unsigned short* pl = (const unsigned short*)&bl;
        #pragma unroll
        for (int j = 0; j < 8; j++) {
            sBh[(bc8 + j) * APAD + bkr] = ph[j];
            sBl[(bc8 + j) * APAD + bkr] = pl[j];
        }
        __syncthreads();

        v8s ah0 = *(const v8s*)&sAh[(wr + l15) * APAD + quad * 8];
        v8s ah1 = *(const v8s*)&sAh[(wr + 16 + l15) * APAD + quad * 8];
        v8s al0 = *(const v8s*)&sAl[(wr + l15) * APAD + quad * 8];
        v8s al1 = *(const v8s*)&sAl[(wr + 16 + l15) * APAD + quad * 8];
        #pragma unroll
        for (int j = 0; j < 2; j++) {
            v8s bh8 = *(const v8s*)&sBh[(wc + j * 16 + l15) * APAD + quad * 8];
            v8s bl8 = *(const v8s*)&sBl[(wc + j * 16 + l15) * APAD + quad * 8];
            acc[0][j] = __builtin_amdgcn_mfma_f32_16x16x32_bf16(ah0, bh8, acc[0][j], 0, 0, 0);
            acc[1][j] = __builtin_amdgcn_mfma_f32_16x16x32_bf16(ah1, bh8, acc[1][j], 0, 0, 0);
            acc[0][j] = __builtin_amdgcn_mfma_f32_16x16x32_bf16(ah0, bl8, acc[0][j], 0, 0, 0);
            acc[1][j] = __builtin_amdgcn_mfma_f32_16x16x32_bf16(ah1, bl8, acc[1][j], 0, 0, 0);
            acc[0][j] = __builtin_amdgcn_mfma_f32_16x16x32_bf16(al0, bh8, acc[0][j], 0, 0, 0);
            acc[1][j] = __builtin_amdgcn_mfma_f32_16x16x32_bf16(al1, bh8, acc[1][j], 0, 0, 0);
        }
        __syncthreads();
    }

    #pragma unroll
    for (int i = 0; i < 2; i++)
        #pragma unroll
        for (int j = 0; j < 2; j++) {
            int rb = w0 + wr + i * 16 + quad * 4;
            int cc = n0 + wc + j * 16 + l15;
            #pragma unroll
            for (int rr = 0; rr < 4; rr++) {
                unsigned short hi, lo;
                split_bf(acc[i][j][rr], hi, lo);
                size_t o = dstb + (size_t)(rb + rr) * NN + cc;
                Mh[o] = hi; Ml[o] = lo;
            }
        }
}

// ---------------- plain -> fragment-major: chunk t = (T*128 + kc)*64 + rowloc ----------------
__global__ void k_m2frag(const unsigned short* __restrict__ Ph, const unsigned short* __restrict__ Pl,
                         unsigned short* __restrict__ Fh, unsigned short* __restrict__ Fl) {
    size_t t = (size_t)blockIdx.x * 256 + threadIdx.x;   // 524288 chunks
    int rowloc = (int)(t & 63);
    int kc = (int)((t >> 6) & 127);
    int T = (int)(t >> 13);
    size_t src = ((size_t)(T * 64 + rowloc) * NN) + kc * 8;
    size_t dst = t * 8;
    *(uint4*)(Fh + dst) = *(const uint4*)(Ph + src);
    *(uint4*)(Fl + dst) = *(const uint4*)(Pl + src);
}

// ---------------- encoder -> XT x-cols (transposed split): XT[b][c][n] ----------------
__global__ void k_encT(const float* __restrict__ x, const float* __restrict__ W_enc,
                       const float* __restrict__ b_enc, const float* __restrict__ emb,
                       unsigned short* __restrict__ XTh, unsigned short* __restrict__ XTl, int t) {
    int b = blockIdx.x >> 6;
    int c = blockIdx.x & 63;
    int n8 = threadIdx.x * 8;
    float w[FF];
    #pragma unroll
    for (int f = 0; f < FF; f++) w[f] = W_enc[f * HH + c];
    float be = b_enc[c];
    unsigned short h8[8], l8[8];
    #pragma unroll
    for (int j = 0; j < 8; j++) {
        int n = n8 + j;
        const float* xr = x + (((size_t)b * TT + t) * NN + n) * FF;
        float acc = be + emb[(size_t)n * HH + c];
        #pragma unroll
        for (int f = 0; f < FF; f++) acc += xr[f] * w[f];
        split_bf(acc, h8[j], l8[j]);
    }
    size_t o = ((size_t)b * 128 + c) * NN + n8;
    *(uint4*)(XTh + o) = *(uint4*)h8;
    *(uint4*)(XTl + o) = *(uint4*)l8;
}

// ---------------- LDS-free stacked hop: fragment loads direct from global ----------------
// M fragment-major; XT is [c][node] (k-contiguous). Block 128 rows x 64 cols, 4 waves 64x32.
// grid (32, ncol64, 16): rt = blockIdx.x: g = rt>>3, node base = (rt&7)*128.
__global__ __launch_bounds__(256) void k_hopF(
        const unsigned short* __restrict__ Mfh, const unsigned short* __restrict__ Mfl,
        const unsigned short* __restrict__ XTh, const unsigned short* __restrict__ XTl,
        int in_off,
        float* __restrict__ Yout, int out_stride, int out_gmul, int out_off) {
    int rt = blockIdx.x;
    int g = rt >> 3;
    int n0 = (rt & 7) * 128;
    int b = blockIdx.z;
    int c0 = in_off + blockIdx.y * 64;

    int tid = threadIdx.x;
    int lane = tid & 63, wave = tid >> 6;
    int rh_ = (wave >> 1) * 64;
    int ch_ = (wave & 1) * 32;
    int l15 = lane & 15, quad = lane >> 4;

    int T = rt * 2 + (wave >> 1);   // 64-row fragment tile
    const unsigned short* Ah = Mfh + (size_t)T * 128 * 64 * 8;
    const unsigned short* Al = Mfl + (size_t)T * 128 * 64 * 8;
    const unsigned short* Xh = XTh + ((size_t)b * 128 + c0 + ch_) * NN;
    const unsigned short* Xl = XTl + ((size_t)b * 128 + c0 + ch_) * NN;

    v4f acc[4][2];
    #pragma unroll
    for (int i = 0; i < 4; i++)
        #pragma unroll
        for (int j = 0; j < 2; j++) { acc[i][j][0]=0.f; acc[i][j][1]=0.f; acc[i][j][2]=0.f; acc[i][j][3]=0.f; }

    for (int k0 = 0; k0 < NN; k0 += 32) {
        int kc = (k0 >> 3) + quad;
        v8s ah[4], al[4], bh[2], bl[2];
        #pragma unroll
        for (int rf = 0; rf < 4; rf++) {
            size_t o = ((size_t)kc * 64 + rf * 16 + l15) * 8;
            ah[rf] = *(const v8s*)(Ah + o);
            al[rf] = *(const v8s*)(Al + o);
        }
        #pragma unroll
        for (int j = 0; j < 2; j++) {
            size_t o = (size_t)(j * 16 + l15) * NN + k0 + quad * 8;
            bh[j] = *(const v8s*)(Xh + o);
            bl[j] = *(const v8s*)(Xl + o);
        }
        #pragma unroll
        for (int rf = 0; rf < 4; rf++)
            #pragma unroll
            for (int j = 0; j < 2; j++) {
                acc[rf][j] = __builtin_amdgcn_mfma_f32_16x16x32_bf16(ah[rf], bh[j], acc[rf][j], 0, 0, 0);
                acc[rf][j] = __builtin_amdgcn_mfma_f32_16x16x32_bf16(ah[rf], bl[j], acc[rf][j], 0, 0, 0);
                acc[rf][j] = __builtin_amdgcn_mfma_f32_16x16x32_bf16(al[rf], bh[j], acc[rf][j], 0, 0, 0);
            }
    }

    float* Y = Yout + (size_t)b * NN * out_stride + out_gmul * g + out_off + blockIdx.y * 64 + ch_;
    #pragma unroll
    for (int rf = 0; rf < 4; rf++)
        #pragma unroll
        for (int j = 0; j < 2; j++) {
            int rbase = n0 + rh_ + rf * 16 + quad * 4;
            int cc = j * 16 + l15;
            #pragma unroll
            for (int rr = 0; rr < 4; rr++)
                Y[(size_t)(rbase + rr) * out_stride + cc] = acc[rf][j][rr];
        }
}

// ---------------- gates: r,u = sigmoid(feats@W+b); rh -> XT h-cols, u -> XT x-cols ----------------
__global__ __launch_bounds__(256) void k_gates(
        const float* __restrict__ feats,
        const float* __restrict__ W_r, const float* __restrict__ W_u,
        const float* __restrict__ b_r, const float* __restrict__ b_u,
        const float* __restrict__ h,
        unsigned short* __restrict__ XTh, unsigned short* __restrict__ XTl) {
    int row0 = blockIdx.x * 32;
    int b = row0 >> 10, n0g = row0 & 1023;
    __shared__ float Fa[16][36];
    __shared__ float Wr[16][68];
    __shared__ float Wu[16][68];
    __shared__ float sTr[64][33];
    __shared__ float sTu[64][33];

    int tid = threadIdx.x;
    int ar = tid >> 3,  ak2 = (tid & 7) * 2;
    int bk = tid >> 4,  bc4 = (tid & 15) * 4;
    int ty = tid >> 4,  tx  = tid & 15;

    float accr[2][4] = {}, accu[2][4] = {};
    for (int k0 = 0; k0 < FS; k0 += 16) {
        float2 fv = *(const float2*)(feats + (size_t)(row0 + ar) * FS + k0 + ak2);
        Fa[ak2 + 0][ar] = fv.x; Fa[ak2 + 1][ar] = fv.y;
        *(float4*)&Wr[bk][bc4] = *(const float4*)(W_r + (size_t)(k0 + bk) * HH + bc4);
        *(float4*)&Wu[bk][bc4] = *(const float4*)(W_u + (size_t)(k0 + bk) * HH + bc4);
        __syncthreads();
        #pragma unroll
        for (int kk = 0; kk < 16; kk++) {
            float a0 = Fa[kk][ty * 2 + 0];
            float a1 = Fa[kk][ty * 2 + 1];
            const float4 r4 = *(const float4*)&Wr[kk][tx * 4];
            const float4 u4 = *(const float4*)&Wu[kk][tx * 4];
            accr[0][0] += a0 * r4.x; accr[0][1] += a0 * r4.y; accr[0][2] += a0 * r4.z; accr[0][3] += a0 * r4.w;
            accr[1][0] += a1 * r4.x; accr[1][1] += a1 * r4.y; accr[1][2] += a1 * r4.z; accr[1][3] += a1 * r4.w;
            accu[0][0] += a0 * u4.x; accu[0][1] += a0 * u4.y; accu[0][2] += a0 * u4.z; accu[0][3] += a0 * u4.w;
            accu[1][0] += a1 * u4.x; accu[1][1] += a1 * u4.y; accu[1][2] += a1 * u4.z; accu[1][3] += a1 * u4.w;
        }
        __syncthreads();
    }
    #pragma unroll
    for (int i = 0; i < 2; i++) {
        int nloc = ty * 2 + i;
        size_t row = row0 + nloc;
        #pragma unroll
        for (int j = 0; j < 4; j++) {
            int c = tx * 4 + j;
            float r = 1.f / (1.f + expf(-(accr[i][j] + b_r[c])));
            float u = 1.f / (1.f + expf(-(accu[i][j] + b_u[c])));
            sTr[c][nloc] = r * h[row * HH + c];
            sTu[c][nloc] = u;
        }
    }
    __syncthreads();
    int c2 = tid >> 2, n8 = (tid & 3) * 8;
    unsigned short rh8[8], rl8[8], uh8[8], ul8[8];
    #pragma unroll
    for (int j = 0; j < 8; j++) {
        split_bf(sTr[c2][n8 + j], rh8[j], rl8[j]);
        split_bf(sTu[c2][n8 + j], uh8[j], ul8[j]);
    }
    size_t oh = ((size_t)b * 128 + 64 + c2) * NN + n0g + n8;
    size_t ou = ((size_t)b * 128 + c2) * NN + n0g + n8;
    *(uint4*)(XTh + oh) = *(uint4*)rh8;
    *(uint4*)(XTl + oh) = *(uint4*)rl8;
    *(uint4*)(XTh + ou) = *(uint4*)uh8;
    *(uint4*)(XTl + ou) = *(uint4*)ul8;
}

// ---------------- candidate + h update; new h -> h f32 AND XT h-cols ----------------
__global__ __launch_bounds__(256) void k_cand(
        const float* __restrict__ feats, const float* __restrict__ W_c,
        const float* __restrict__ b_c,
        const unsigned short* __restrict__ XTh, const unsigned short* __restrict__ XTl,
        float* __restrict__ h,
        unsigned short* __restrict__ XTho, unsigned short* __restrict__ XTlo) {
    int row0 = blockIdx.x * 32;
    int b = row0 >> 10, n0g = row0 & 1023;
    __shared__ float Fa[16][36];
    __shared__ float Wb[16][68];
    __shared__ float sT[64][33];

    int tid = threadIdx.x;
    int ar = tid >> 3,  ak2 = (tid & 7) * 2;
    int bk = tid >> 4,  bc4 = (tid & 15) * 4;
    int ty = tid >> 4,  tx  = tid & 15;

    float acc[2][4] = {};
    for (int k0 = 0; k0 < FS; k0 += 16) {
        float2 fv = *(const float2*)(feats + (size_t)(row0 + ar) * FS + k0 + ak2);
        Fa[ak2 + 0][ar] = fv.x; Fa[ak2 + 1][ar] = fv.y;
        *(float4*)&Wb[bk][bc4] = *(const float4*)(W_c + (size_t)(k0 + bk) * HH + bc4);
        __syncthreads();
        #pragma unroll
        for (int kk = 0; kk < 16; kk++) {
            float a0 = Fa[kk][ty * 2 + 0];
            float a1 = Fa[kk][ty * 2 + 1];
            const float4 b4 = *(const float4*)&Wb[kk][tx * 4];
            acc[0][0] += a0 * b4.x; acc[0][1] += a0 * b4.y; acc[0][2] += a0 * b4.z; acc[0][3] += a0 * b4.w;
            acc[1][0] += a1 * b4.x; acc[1][1] += a1 * b4.y; acc[1][2] += a1 * b4.z; acc[1][3] += a1 * b4.w;
        }
        __syncthreads();
    }
    #pragma unroll
    for (int i = 0; i < 2; i++) {
        int nloc = ty * 2 + i;
        size_t row = row0 + nloc;
        #pragma unroll
        for (int j = 0; j < 4; j++) {
            int c = tx * 4 + j;
            float cv = tanhf(acc[i][j] + b_c[c]);
            size_t uo = ((size_t)b * 128 + c) * NN + n0g + nloc;
            float u = bfu2f(XTh[uo]) + bfu2f(XTl[uo]);
            float hv = h[row * HH + c];
            float hn = u * hv + (1.f - u) * cv;
            h[row * HH + c] = hn;
            sT[c][nloc] = hn;
        }
    }
    __syncthreads();
    int c2 = tid >> 2, n8 = (tid & 3) * 8;
    unsigned short h8[8], l8[8];
    #pragma unroll
    for (int j = 0; j < 8; j++) split_bf(sT[c2][n8 + j], h8[j], l8[j]);
    size_t oh = ((size_t)b * 128 + 64 + c2) * NN + n0g + n8;
    *(uint4*)(XTho + oh) = *(uint4*)h8;
    *(uint4*)(XTlo + oh) = *(uint4*)l8;
}

// ---------------- DiffConv operator build ----------------
__global__ void k_deg(const int* __restrict__ ei32, const float* __restrict__ ew,
                      float* __restrict__ degd, float* __restrict__ degs) {
    int e = blockIdx.x * 256 + threadIdx.x;
    float w = ew[e];
    atomicAdd(&degd[ei32[EE + e]], w);
    atomicAdd(&degs[ei32[e]], w);
}
__global__ void k_spadd(const int* __restrict__ ei32, const float* __restrict__ ew,
                        const float* __restrict__ degd, const float* __restrict__ degs,
                        float* __restrict__ temp) {
    int e = blockIdx.x * 256 + threadIdx.x;
    int s = ei32[e], d = ei32[EE + e];
    float w = ew[e];
    float dd = degd[d], ds = degs[s];
    float wfv = dd > 0.f ? w / dd : 0.f;
    float wbv = ds > 0.f ? w / ds : 0.f;
    atomicAdd(&temp[(size_t)d * NN + s], wfv);
    atomicAdd(&temp[(size_t)NN * NN + (size_t)s * NN + d], wbv);
}
__global__ void k_spconv(const float* __restrict__ temp,
                         unsigned short* __restrict__ Mh, unsigned short* __restrict__ Ml) {
    size_t i0 = ((size_t)blockIdx.x * 256 + threadIdx.x) * 8;
    size_t dst = (i0 < (size_t)NN * NN) ? i0 : i0 + (size_t)NN * NN;
    unsigned short h8[8], l8[8];
    #pragma unroll
    for (int j = 0; j < 8; j++) split_bf(temp[i0 + j], h8[j], l8[j]);
    *(uint4*)(Mh + dst) = *(uint4*)h8;
    *(uint4*)(Ml + dst) = *(uint4*)l8;
}

__global__ void k_featd_h(const float* __restrict__ h, float* __restrict__ featd) {
    size_t idx = (size_t)blockIdx.x * 256 + threadIdx.x;
    size_t row = idx >> 6; int c = (int)(idx & 63);
    featd[row * DIN + c] = h[idx];
}

__global__ __launch_bounds__(256) void k_z(
        const float* __restrict__ featd, const float* __restrict__ W_diff,
        const float* __restrict__ b_diff, float* __restrict__ z) {
    int row0 = blockIdx.x * 4;
    __shared__ float sF[4 * DIN];
    int tid = threadIdx.x;
    for (int i = tid; i < 4 * DIN / 4; i += 256)
        *(float4*)&sF[i * 4] = *(const float4*)&featd[(size_t)row0 * DIN + (size_t)i * 4];
    __syncthreads();
    int lr = tid >> 6, ch = tid & 63;
    const float* f = &sF[lr * DIN];
    float acc = b_diff[ch];
    for (int k = 0; k < DIN; k++) acc += f[k] * W_diff[k * HH + ch];
    z[(size_t)(row0 + lr) * HH + ch] = acc;
}

__global__ void k_dec(const float* __restrict__ z, const float* __restrict__ W_dec,
                      const float* __restrict__ b_dec, float* __restrict__ out) {
    size_t idx = (size_t)blockIdx.x * 256 + threadIdx.x;
    size_t row = idx / ODIM; int o = (int)(idx % ODIM);
    const float* zr = z + row * HH;
    float acc = b_dec[o];
    for (int k = 0; k < HH; k++) acc += zr[k] * W_dec[k * ODIM + o];
    int b = (int)(row >> 10), n = (int)(row & 1023);
    int t = o >> 3, f = o & 7;
    out[(((size_t)b * TT + t) * NN + n) * FF + f] = acc;
}

extern "C" void kernel_launch(void* const* d_in, const int* in_sizes, int n_in,
                              void* d_out, int out_size, void* d_ws, size_t ws_size,
                              hipStream_t stream) {
    const float* x      = (const float*)d_in[0];
    const int*   eiraw  = (const int*)  d_in[1];
    const float* ew     = (const float*)d_in[2];
    const float* adj    = (const float*)d_in[3];
    const float* W_enc  = (const float*)d_in[4];
    const float* b_enc  = (const float*)d_in[5];
    const float* emb    = (const float*)d_in[6];
    const float* W_r    = (const float*)d_in[7];
    const float* b_r    = (const float*)d_in[8];
    const float* W_u    = (const float*)d_in[9];
    const float* b_u    = (const float*)d_in[10];
    const float* W_c    = (const float*)d_in[11];
    const float* b_c    = (const float*)d_in[12];
    const float* W_diff = (const float*)d_in[13];
    const float* b_diff = (const float*)d_in[14];
    const float* W_dec  = (const float*)d_in[15];
    const float* b_dec  = (const float*)d_in[16];

    // ---- workspace: 60.0 MiB ----
    unsigned short* Mfh = (unsigned short*)d_ws;          // frag hi 8 MiB
    unsigned short* Mfl = Mfh + (size_t)4096 * NN;        // frag lo 8 MiB
    unsigned short* XTh = Mfl + (size_t)4096 * NN;        // 4 MiB
    unsigned short* XTl = XTh + (size_t)BB * 128 * NN;    // 4 MiB
    float* feats = (float*)(XTl + (size_t)BB * 128 * NN); // 32 MiB
    float* h     = feats + (size_t)BB * NN * FS;          // 4 MiB
    // overlays inside feats:
    unsigned short* Mph = (unsigned short*)feats;         // plain hi 8 MiB  [feats+0..8)
    unsigned short* Mpl = Mph + (size_t)4096 * NN;        // plain lo 8 MiB  [8..16)
    float* sptmp = feats + (size_t)4 * 1024 * 1024;       // 8 MiB           [16..24)
    float* rinv  = feats + (size_t)6 * 1024 * 1024;       // [24..) pre-loop / readout zone
    float* cinv  = rinv + NN;
    int*   eifl  = (int*)(cinv + NN);
    int*   ei32  = eifl + 4;
    float* degd  = (float*)(ei32 + 2 * EE);
    float* degs  = degd + NN;
    float* featd = feats;                                 // 20 MiB (after m2frag)
    float* z     = h;                                     // h dead after k_featd_h

    hipMemsetAsync(h, 0, (size_t)BB * NN * HH * 4, stream);

    // ---- build plain M = [Af; Af^2; Ab; Ab^2], then convert to fragment-major ----
    k_rowsum<<<NN, 256, 0, stream>>>(adj, rinv);
    k_colsum<<<NN / 256, 256, 0, stream>>>(adj, cinv);
    k_prepA<<<dim3(16, 16), 256, 0, stream>>>(adj, rinv, cinv, Mph, Mpl);
    k_msq<<<dim3(16, 16, 2), 256, 0, stream>>>(Mph, Mpl);
    k_m2frag<<<2048, 256, 0, stream>>>(Mph, Mpl, Mfh, Mfl);
    hipMemsetAsync(XTh, 0, (size_t)BB * 128 * NN * 2 * 2, stream);  // XTh+XTl (h=0 at t=0)

    for (int t = 0; t < TT; t++) {
        k_encT<<<BB * 64, 128, 0, stream>>>(x, W_enc, b_enc, emb, XTh, XTl, t);
        // 4 operators x [x|h] -> feats cols g*128 + 0..127
        k_hopF<<<dim3(32, 2, 16), 256, 0, stream>>>(Mfh, Mfl, XTh, XTl, 0, feats, FS, 128, 0);
        // gates: rh -> XT h-cols, u -> XT x-cols
        k_gates<<<BB * NN / 32, 256, 0, stream>>>(feats, W_r, W_u, b_r, b_u, h, XTh, XTl);
        // 4 operators @ rh -> feats h-cols
        k_hopF<<<dim3(32, 1, 16), 256, 0, stream>>>(Mfh, Mfl, XTh, XTl, 64, feats, FS, 128, 64);
        // candidate + h update
        k_cand<<<BB * NN / 32, 256, 0, stream>>>(feats, W_c, b_c, XTh, XTl, h, XTh, XTl);
    }

    // ---- DiffConv readout ----
    k_ei_detect<<<1, 256, 0, stream>>>(eiraw, eifl);
    k_ei_norm<<<2 * EE / 256, 256, 0, stream>>>(eiraw, eifl, ei32);
    hipMemsetAsync(degd, 0, (size_t)2 * NN * 4, stream);
    hipMemsetAsync(sptmp, 0, (size_t)2 * NN * NN * 4, stream);
    k_deg<<<EE / 256, 256, 0, stream>>>(ei32, ew, degd, degs);
    k_spadd<<<EE / 256, 256, 0, stream>>>(ei32, ew, degd, degs, sptmp);
    k_spconv<<<2 * NN * NN / (256 * 8), 256, 0, stream>>>(sptmp, Mph, Mpl);  // Sf,Sb -> plain g0,g2
    k_msq<<<dim3(16, 16, 2), 256, 0, stream>>>(Mph, Mpl);                    // squares -> plain g1,g3
    k_m2frag<<<2048, 256, 0, stream>>>(Mph, Mpl, Mfh, Mfl);                  // -> frag (GRU M dead)
    k_featd_h<<<BB * NN * HH / 256, 256, 0, stream>>>(h, featd);             // clobbers plain M (done)
    // [Sf;Sf2;Sb;Sb2] @ h (hT in XT h-cols) -> featd cols 64 + g*64
    k_hopF<<<dim3(32, 1, 16), 256, 0, stream>>>(Mfh, Mfl, XTh, XTl, 64, featd, DIN, 64, 64);
    k_z<<<BB * NN / 4, 256, 0, stream>>>(featd, W_diff, b_diff, z);
    k_dec<<<(BB * NN * ODIM) / 256, 256, 0, stream>>>(z, W_dec, b_dec, (float*)d_out);
}

// Round 15
// 2413.620 us; speedup vs baseline: 1.3536x; 1.3536x over previous
//
#include <hip/hip_runtime.h>
#include <hip/hip_bf16.h>
#include <math.h>

#define BB 16
#define TT 12
#define NN 1024
#define FF 8
#define HH 64
#define EE 32768
#define DIN 320   // H * (2K+1)
#define ODIM 96   // F * HORIZON
#define FS 512    // feats cols: [Af|Af2|Ab|Ab2] x [x(64)|h(64)]
#define APAD 40   // k_msq LDS row stride

typedef short v8s __attribute__((ext_vector_type(8)));
typedef float v4f __attribute__((ext_vector_type(4)));

__device__ __forceinline__ unsigned short f2bf_rne(float v) {
    unsigned u = __float_as_uint(v);
    u += 0x7FFF + ((u >> 16) & 1);
    return (unsigned short)(u >> 16);
}
__device__ __forceinline__ float bfu2f(unsigned short u) {
    return __uint_as_float((unsigned)u << 16);
}
__device__ __forceinline__ void split_bf(float v, unsigned short& hi, unsigned short& lo) {
    hi = f2bf_rne(v);
    lo = f2bf_rne(v - bfu2f(hi));
}
// async global->LDS, 16B per lane; LDS dst = wave-uniform base + lane*16
__device__ __forceinline__ void gl_lds16(const void* g, void* l) {
    __builtin_amdgcn_global_load_lds(
        (const __attribute__((address_space(1))) unsigned int*)g,
        (__attribute__((address_space(3))) unsigned int*)l, 16, 0, 0);
}

// ---------------- edge_index insurance ----------------
__global__ void k_ei_detect(const int* __restrict__ ei_raw, int* __restrict__ flag) {
    __shared__ int s[256];
    s[threadIdx.x] = ei_raw[2 * threadIdx.x + 1];
    __syncthreads();
    for (int st = 128; st > 0; st >>= 1) {
        if (threadIdx.x < st) s[threadIdx.x] |= s[threadIdx.x + st];
        __syncthreads();
    }
    if (threadIdx.x == 0) flag[0] = (s[0] == 0) ? 1 : 0;
}
__global__ void k_ei_norm(const int* __restrict__ ei_raw, const int* __restrict__ flag,
                          int* __restrict__ ei32) {
    int j = blockIdx.x * 256 + threadIdx.x;
    ei32[j] = flag[0] ? ei_raw[2 * j] : ei_raw[j];
}

// ---------------- support normalization ----------------
__global__ void k_rowsum(const float* __restrict__ adj, float* __restrict__ rinv) {
    __shared__ float s[256];
    int i = blockIdx.x;
    float acc = 0.f;
    for (int j = threadIdx.x; j < NN; j += 256) acc += adj[i * NN + j];
    s[threadIdx.x] = acc;
    __syncthreads();
    for (int st = 128; st > 0; st >>= 1) {
        if (threadIdx.x < st) s[threadIdx.x] += s[threadIdx.x + st];
        __syncthreads();
    }
    if (threadIdx.x == 0) rinv[i] = (s[0] != 0.f) ? 1.f / s[0] : 0.f;
}
__global__ void k_colsum(const float* __restrict__ adj, float* __restrict__ cinv) {
    int j = blockIdx.x * 256 + threadIdx.x;
    float acc = 0.f;
    for (int i = 0; i < NN; i++) acc += adj[i * NN + j];
    cinv[j] = (acc != 0.f) ? 1.f / acc : 0.f;
}

// ---------------- Af -> plain rows 0..1023, Ab -> plain rows 2048..3071 (split bf16) ----------------
__global__ __launch_bounds__(256) void k_prepA(
        const float* __restrict__ adj, const float* __restrict__ rinv,
        const float* __restrict__ cinv,
        unsigned short* __restrict__ Mh, unsigned short* __restrict__ Ml) {
    int w0 = blockIdx.x * 64, v0 = blockIdx.y * 64;
    __shared__ float T[64][68];
    int row = threadIdx.x >> 2, cs = (threadIdx.x & 3) * 16;
    #pragma unroll
    for (int j = 0; j < 4; j++)
        *(float4*)&T[row][cs + j * 4] = *(const float4*)(adj + (size_t)(w0 + row) * NN + v0 + cs + j * 4);
    __syncthreads();
    {
        float sc = rinv[w0 + row];
        unsigned short h8[16], l8[16];
        #pragma unroll
        for (int j = 0; j < 16; j++) split_bf(T[row][cs + j] * sc, h8[j], l8[j]);
        size_t ofs = (size_t)(w0 + row) * NN + v0 + cs;
        ((uint4*)(Mh + ofs))[0] = *(uint4*)&h8[0];
        ((uint4*)(Mh + ofs))[1] = *(uint4*)&h8[8];
        ((uint4*)(Ml + ofs))[0] = *(uint4*)&l8[0];
        ((uint4*)(Ml + ofs))[1] = *(uint4*)&l8[8];
    }
    {
        float sc = cinv[v0 + row];
        unsigned short h8[16], l8[16];
        #pragma unroll
        for (int j = 0; j < 16; j++) split_bf(T[cs + j][row] * sc, h8[j], l8[j]);
        size_t ofs = (size_t)2048 * NN + (size_t)(v0 + row) * NN + w0 + cs;
        ((uint4*)(Mh + ofs))[0] = *(uint4*)&h8[0];
        ((uint4*)(Mh + ofs))[1] = *(uint4*)&h8[8];
        ((uint4*)(Ml + ofs))[0] = *(uint4*)&l8[0];
        ((uint4*)(Ml + ofs))[1] = *(uint4*)&l8[8];
    }
}

// ---------------- plain M rows (zz) squared: rows zz*2048 -> zz*2048+1024 ----------------
__global__ __launch_bounds__(256) void k_msq(
        unsigned short* __restrict__ Mh, unsigned short* __restrict__ Ml) {
    int zz = blockIdx.z;
    size_t srcb = (size_t)zz * 2048 * NN;
    size_t dstb = srcb + (size_t)1024 * NN;
    int w0 = blockIdx.x * 64, n0 = blockIdx.y * 64;

    __shared__ unsigned short sAh[64 * APAD];
    __shared__ unsigned short sAl[64 * APAD];
    __shared__ unsigned short sBh[64 * APAD];
    __shared__ unsigned short sBl[64 * APAD];

    int tid = threadIdx.x;
    int lane = tid & 63, wave = tid >> 6;
    int wr = (wave >> 1) * 32, wc = (wave & 1) * 32;
    int l15 = lane & 15, quad = lane >> 4;
    int arow = tid >> 2, akk = (tid & 3) * 8;
    int bkr = tid & 31, bc8 = (tid >> 5) * 8;

    v4f acc[2][2];
    #pragma unroll
    for (int i = 0; i < 2; i++)
        #pragma unroll
        for (int j = 0; j < 2; j++) { acc[i][j][0]=0.f; acc[i][j][1]=0.f; acc[i][j][2]=0.f; acc[i][j][3]=0.f; }

    for (int k0 = 0; k0 < NN; k0 += 32) {
        size_t aofs = srcb + (size_t)(w0 + arow) * NN + k0 + akk;
        *(uint4*)&sAh[arow * APAD + akk] = *(const uint4*)(Mh + aofs);
        *(uint4*)&sAl[arow * APAD + akk] = *(const uint4*)(Ml + aofs);
        size_t bofs = srcb + (size_t)(k0 + bkr) * NN + n0 + bc8;
        uint4 bh = *(const uint4*)(Mh + bofs);
        uint4 bl = *(const uint4*)(Ml + bofs);
        const unsigned short* ph = (const unsigned short*)&bh;
        const unsigned short* pl = (const unsigned short*)&bl;
        #pragma unroll
        for (int j = 0; j < 8; j++) {
            sBh[(bc8 + j) * APAD + bkr] = ph[j];
            sBl[(bc8 + j) * APAD + bkr] = pl[j];
        }
        __syncthreads();

        v8s ah0 = *(const v8s*)&sAh[(wr + l15) * APAD + quad * 8];
        v8s ah1 = *(const v8s*)&sAh[(wr + 16 + l15) * APAD + quad * 8];
        v8s al0 = *(const v8s*)&sAl[(wr + l15) * APAD + quad * 8];
        v8s al1 = *(const v8s*)&sAl[(wr + 16 + l15) * APAD + quad * 8];
        #pragma unroll
        for (int j = 0; j < 2; j++) {
            v8s bh8 = *(const v8s*)&sBh[(wc + j * 16 + l15) * APAD + quad * 8];
            v8s bl8 = *(const v8s*)&sBl[(wc + j * 16 + l15) * APAD + quad * 8];
            acc[0][j] = __builtin_amdgcn_mfma_f32_16x16x32_bf16(ah0, bh8, acc[0][j], 0, 0, 0);
            acc[1][j] = __builtin_amdgcn_mfma_f32_16x16x32_bf16(ah1, bh8, acc[1][j], 0, 0, 0);
            acc[0][j] = __builtin_amdgcn_mfma_f32_16x16x32_bf16(ah0, bl8, acc[0][j], 0, 0, 0);
            acc[1][j] = __builtin_amdgcn_mfma_f32_16x16x32_bf16(ah1, bl8, acc[1][j], 0, 0, 0);
            acc[0][j] = __builtin_amdgcn_mfma_f32_16x16x32_bf16(al0, bh8, acc[0][j], 0, 0, 0);
            acc[1][j] = __builtin_amdgcn_mfma_f32_16x16x32_bf16(al1, bh8, acc[1][j], 0, 0, 0);
        }
        __syncthreads();
    }

    #pragma unroll
    for (int i = 0; i < 2; i++)
        #pragma unroll
        for (int j = 0; j < 2; j++) {
            int rb = w0 + wr + i * 16 + quad * 4;
            int cc = n0 + wc + j * 16 + l15;
            #pragma unroll
            for (int rr = 0; rr < 4; rr++) {
                unsigned short hi, lo;
                split_bf(acc[i][j][rr], hi, lo);
                size_t o = dstb + (size_t)(rb + rr) * NN + cc;
                Mh[o] = hi; Ml[o] = lo;
            }
        }
}

// ---------------- plain -> fragment-major: chunk t = (T*128 + kc)*64 + rowloc ----------------
__global__ void k_m2frag(const unsigned short* __restrict__ Ph, const unsigned short* __restrict__ Pl,
                         unsigned short* __restrict__ Fh, unsigned short* __restrict__ Fl) {
    size_t t = (size_t)blockIdx.x * 256 + threadIdx.x;
    int rowloc = (int)(t & 63);
    int kc = (int)((t >> 6) & 127);
    int T = (int)(t >> 13);
    size_t src = ((size_t)(T * 64 + rowloc) * NN) + kc * 8;
    size_t dst = t * 8;
    *(uint4*)(Fh + dst) = *(const uint4*)(Ph + src);
    *(uint4*)(Fl + dst) = *(const uint4*)(Pl + src);
}

// ---------------- encoder -> XT x-cols (transposed split): XT[b][c][n] ----------------
__global__ void k_encT(const float* __restrict__ x, const float* __restrict__ W_enc,
                       const float* __restrict__ b_enc, const float* __restrict__ emb,
                       unsigned short* __restrict__ XTh, unsigned short* __restrict__ XTl, int t) {
    int b = blockIdx.x >> 6;
    int c = blockIdx.x & 63;
    int n8 = threadIdx.x * 8;
    float w[FF];
    #pragma unroll
    for (int f = 0; f < FF; f++) w[f] = W_enc[f * HH + c];
    float be = b_enc[c];
    unsigned short h8[8], l8[8];
    #pragma unroll
    for (int j = 0; j < 8; j++) {
        int n = n8 + j;
        const float* xr = x + (((size_t)b * TT + t) * NN + n) * FF;
        float acc = be + emb[(size_t)n * HH + c];
        #pragma unroll
        for (int f = 0; f < FF; f++) acc += xr[f] * w[f];
        split_bf(acc, h8[j], l8[j]);
    }
    size_t o = ((size_t)b * 128 + c) * NN + n8;
    *(uint4*)(XTh + o) = *(uint4*)h8;
    *(uint4*)(XTl + o) = *(uint4*)l8;
}

// ---------------- async-LDS stacked hop (m97-style) ----------------
// M fragment-major, XT [c][n]. Block 128 rows x 64 cols, 4 waves (64x32 each).
// Staging: 24 x 1KB global_load_lds(16B) segments/K-tile, lane-ordered LDS -> conflict-free b128 reads.
__global__ __launch_bounds__(256) void k_hopA(
        const unsigned short* __restrict__ Mfh, const unsigned short* __restrict__ Mfl,
        const unsigned short* __restrict__ XTh, const unsigned short* __restrict__ XTl,
        int in_off,
        float* __restrict__ Yout, int out_stride, int out_gmul, int out_off) {
    int rt = blockIdx.x;
    int g = rt >> 3;
    int n0 = (rt & 7) * 128;
    int b = blockIdx.z;
    int c0 = in_off + blockIdx.y * 64;

    __shared__ unsigned short sA[16 * 512];   // [half2][hl2][rf4] x 1KB
    __shared__ unsigned short sX[8 * 512];    // [cj4][hl2] x 1KB

    int tid = threadIdx.x;
    int lane = tid & 63, wave = tid >> 6;
    int half = wave >> 1;           // A row-half this wave consumes
    int ch_ = (wave & 1) * 32;
    int l15 = lane & 15, quad = lane >> 4;

    const unsigned short* Xhb = XTh + (size_t)b * 128 * NN;
    const unsigned short* Xlb = XTl + (size_t)b * 128 * NN;

    v4f acc[4][2];
    #pragma unroll
    for (int i = 0; i < 4; i++)
        #pragma unroll
        for (int j = 0; j < 2; j++) { acc[i][j][0]=0.f; acc[i][j][1]=0.f; acc[i][j][2]=0.f; acc[i][j][3]=0.f; }

    for (int k0 = 0; k0 < NN; k0 += 32) {
        // issue this wave's 6 segments (ids: wave, wave+4, ..., wave+20)
        #pragma unroll
        for (int s = 0; s < 6; s++) {
            int id = wave + s * 4;
            if (id < 16) {
                int ah = id >> 3, ahl = (id >> 2) & 1, rf = id & 3;
                const unsigned short* src = (ahl ? Mfl : Mfh) +
                    ((size_t)(rt * 2 + ah) * 8192 + (size_t)((k0 >> 3) + quad) * 64 + rf * 16 + l15) * 8;
                gl_lds16(src, &sA[id * 512]);
            } else {
                int xi = id - 16, cj = xi >> 1, xhl = xi & 1;
                const unsigned short* src = (xhl ? Xlb : Xhb) +
                    (size_t)(c0 + cj * 16 + l15) * NN + k0 + quad * 8;
                gl_lds16(src, &sX[xi * 512]);
            }
        }
        __syncthreads();   // drains vmcnt -> staged data visible

        int lu = lane * 8;   // lane*16B in ushorts
        v8s ah[4], al[4];
        #pragma unroll
        for (int rf = 0; rf < 4; rf++) {
            ah[rf] = *(const v8s*)&sA[(half * 8 + rf) * 512 + lu];
            al[rf] = *(const v8s*)&sA[(half * 8 + 4 + rf) * 512 + lu];
        }
        v8s bh[2], bl[2];
        #pragma unroll
        for (int j = 0; j < 2; j++) {
            int cj = (wave & 1) * 2 + j;
            bh[j] = *(const v8s*)&sX[(cj * 2 + 0) * 512 + lu];
            bl[j] = *(const v8s*)&sX[(cj * 2 + 1) * 512 + lu];
        }
        #pragma unroll
        for (int rf = 0; rf < 4; rf++)
            #pragma unroll
            for (int j = 0; j < 2; j++) {
                acc[rf][j] = __builtin_amdgcn_mfma_f32_16x16x32_bf16(ah[rf], bh[j], acc[rf][j], 0, 0, 0);
                acc[rf][j] = __builtin_amdgcn_mfma_f32_16x16x32_bf16(ah[rf], bl[j], acc[rf][j], 0, 0, 0);
                acc[rf][j] = __builtin_amdgcn_mfma_f32_16x16x32_bf16(al[rf], bh[j], acc[rf][j], 0, 0, 0);
            }
        __syncthreads();   // all reads done before next overwrite
    }

    float* Y = Yout + (size_t)b * NN * out_stride + out_gmul * g + out_off + blockIdx.y * 64 + ch_;
    #pragma unroll
    for (int rf = 0; rf < 4; rf++)
        #pragma unroll
        for (int j = 0; j < 2; j++) {
            int rbase = n0 + half * 64 + rf * 16 + quad * 4;
            int cc = j * 16 + l15;
            #pragma unroll
            for (int rr = 0; rr < 4; rr++)
                Y[(size_t)(rbase + rr) * out_stride + cc] = acc[rf][j][rr];
        }
}

// ---------------- gates: r,u = sigmoid(feats@W+b); rh -> XT h-cols, u -> XT x-cols ----------------
__global__ __launch_bounds__(256) void k_gates(
        const float* __restrict__ feats,
        const float* __restrict__ W_r, const float* __restrict__ W_u,
        const float* __restrict__ b_r, const float* __restrict__ b_u,
        const float* __restrict__ h,
        unsigned short* __restrict__ XTh, unsigned short* __restrict__ XTl) {
    int row0 = blockIdx.x * 32;
    int b = row0 >> 10, n0g = row0 & 1023;
    __shared__ float Fa[16][36];
    __shared__ float Wr[16][68];
    __shared__ float Wu[16][68];
    __shared__ float sTr[64][33];
    __shared__ float sTu[64][33];

    int tid = threadIdx.x;
    int ar = tid >> 3,  ak2 = (tid & 7) * 2;
    int bk = tid >> 4,  bc4 = (tid & 15) * 4;
    int ty = tid >> 4,  tx  = tid & 15;

    float accr[2][4] = {}, accu[2][4] = {};
    for (int k0 = 0; k0 < FS; k0 += 16) {
        float2 fv = *(const float2*)(feats + (size_t)(row0 + ar) * FS + k0 + ak2);
        Fa[ak2 + 0][ar] = fv.x; Fa[ak2 + 1][ar] = fv.y;
        *(float4*)&Wr[bk][bc4] = *(const float4*)(W_r + (size_t)(k0 + bk) * HH + bc4);
        *(float4*)&Wu[bk][bc4] = *(const float4*)(W_u + (size_t)(k0 + bk) * HH + bc4);
        __syncthreads();
        #pragma unroll
        for (int kk = 0; kk < 16; kk++) {
            float a0 = Fa[kk][ty * 2 + 0];
            float a1 = Fa[kk][ty * 2 + 1];
            const float4 r4 = *(const float4*)&Wr[kk][tx * 4];
            const float4 u4 = *(const float4*)&Wu[kk][tx * 4];
            accr[0][0] += a0 * r4.x; accr[0][1] += a0 * r4.y; accr[0][2] += a0 * r4.z; accr[0][3] += a0 * r4.w;
            accr[1][0] += a1 * r4.x; accr[1][1] += a1 * r4.y; accr[1][2] += a1 * r4.z; accr[1][3] += a1 * r4.w;
            accu[0][0] += a0 * u4.x; accu[0][1] += a0 * u4.y; accu[0][2] += a0 * u4.z; accu[0][3] += a0 * u4.w;
            accu[1][0] += a1 * u4.x; accu[1][1] += a1 * u4.y; accu[1][2] += a1 * u4.z; accu[1][3] += a1 * u4.w;
        }
        __syncthreads();
    }
    #pragma unroll
    for (int i = 0; i < 2; i++) {
        int nloc = ty * 2 + i;
        size_t row = row0 + nloc;
        #pragma unroll
        for (int j = 0; j < 4; j++) {
            int c = tx * 4 + j;
            float r = 1.f / (1.f + expf(-(accr[i][j] + b_r[c])));
            float u = 1.f / (1.f + expf(-(accu[i][j] + b_u[c])));
            sTr[c][nloc] = r * h[row * HH + c];
            sTu[c][nloc] = u;
        }
    }
    __syncthreads();
    int c2 = tid >> 2, n8 = (tid & 3) * 8;
    unsigned short rh8[8], rl8[8], uh8[8], ul8[8];
    #pragma unroll
    for (int j = 0; j < 8; j++) {
        split_bf(sTr[c2][n8 + j], rh8[j], rl8[j]);
        split_bf(sTu[c2][n8 + j], uh8[j], ul8[j]);
    }
    size_t oh = ((size_t)b * 128 + 64 + c2) * NN + n0g + n8;
    size_t ou = ((size_t)b * 128 + c2) * NN + n0g + n8;
    *(uint4*)(XTh + oh) = *(uint4*)rh8;
    *(uint4*)(XTl + oh) = *(uint4*)rl8;
    *(uint4*)(XTh + ou) = *(uint4*)uh8;
    *(uint4*)(XTl + ou) = *(uint4*)ul8;
}

// ---------------- candidate + h update; new h -> h f32 AND XT h-cols ----------------
__global__ __launch_bounds__(256) void k_cand(
        const float* __restrict__ feats, const float* __restrict__ W_c,
        const float* __restrict__ b_c,
        const unsigned short* __restrict__ XTh, const unsigned short* __restrict__ XTl,
        float* __restrict__ h,
        unsigned short* __restrict__ XTho, unsigned short* __restrict__ XTlo) {
    int row0 = blockIdx.x * 32;
    int b = row0 >> 10, n0g = row0 & 1023;
    __shared__ float Fa[16][36];
    __shared__ float Wb[16][68];
    __shared__ float sT[64][33];

    int tid = threadIdx.x;
    int ar = tid >> 3,  ak2 = (tid & 7) * 2;
    int bk = tid >> 4,  bc4 = (tid & 15) * 4;
    int ty = tid >> 4,  tx  = tid & 15;

    float acc[2][4] = {};
    for (int k0 = 0; k0 < FS; k0 += 16) {
        float2 fv = *(const float2*)(feats + (size_t)(row0 + ar) * FS + k0 + ak2);
        Fa[ak2 + 0][ar] = fv.x; Fa[ak2 + 1][ar] = fv.y;
        *(float4*)&Wb[bk][bc4] = *(const float4*)(W_c + (size_t)(k0 + bk) * HH + bc4);
        __syncthreads();
        #pragma unroll
        for (int kk = 0; kk < 16; kk++) {
            float a0 = Fa[kk][ty * 2 + 0];
            float a1 = Fa[kk][ty * 2 + 1];
            const float4 b4 = *(const float4*)&Wb[kk][tx * 4];
            acc[0][0] += a0 * b4.x; acc[0][1] += a0 * b4.y; acc[0][2] += a0 * b4.z; acc[0][3] += a0 * b4.w;
            acc[1][0] += a1 * b4.x; acc[1][1] += a1 * b4.y; acc[1][2] += a1 * b4.z; acc[1][3] += a1 * b4.w;
        }
        __syncthreads();
    }
    #pragma unroll
    for (int i = 0; i < 2; i++) {
        int nloc = ty * 2 + i;
        size_t row = row0 + nloc;
        #pragma unroll
        for (int j = 0; j < 4; j++) {
            int c = tx * 4 + j;
            float cv = tanhf(acc[i][j] + b_c[c]);
            size_t uo = ((size_t)b * 128 + c) * NN + n0g + nloc;
            float u = bfu2f(XTh[uo]) + bfu2f(XTl[uo]);
            float hv = h[row * HH + c];
            float hn = u * hv + (1.f - u) * cv;
            h[row * HH + c] = hn;
            sT[c][nloc] = hn;
        }
    }
    __syncthreads();
    int c2 = tid >> 2, n8 = (tid & 3) * 8;
    unsigned short h8[8], l8[8];
    #pragma unroll
    for (int j = 0; j < 8; j++) split_bf(sT[c2][n8 + j], h8[j], l8[j]);
    size_t oh = ((size_t)b * 128 + 64 + c2) * NN + n0g + n8;
    *(uint4*)(XTho + oh) = *(uint4*)h8;
    *(uint4*)(XTlo + oh) = *(uint4*)l8;
}

// ---------------- DiffConv operator build ----------------
__global__ void k_deg(const int* __restrict__ ei32, const float* __restrict__ ew,
                      float* __restrict__ degd, float* __restrict__ degs) {
    int e = blockIdx.x * 256 + threadIdx.x;
    float w = ew[e];
    atomicAdd(&degd[ei32[EE + e]], w);
    atomicAdd(&degs[ei32[e]], w);
}
__global__ void k_spadd(const int* __restrict__ ei32, const float* __restrict__ ew,
                        const float* __restrict__ degd, const float* __restrict__ degs,
                        float* __restrict__ temp) {
    int e = blockIdx.x * 256 + threadIdx.x;
    int s = ei32[e], d = ei32[EE + e];
    float w = ew[e];
    float dd = degd[d], ds = degs[s];
    float wfv = dd > 0.f ? w / dd : 0.f;
    float wbv = ds > 0.f ? w / ds : 0.f;
    atomicAdd(&temp[(size_t)d * NN + s], wfv);
    atomicAdd(&temp[(size_t)NN * NN + (size_t)s * NN + d], wbv);
}
__global__ void k_spconv(const float* __restrict__ temp,
                         unsigned short* __restrict__ Mh, unsigned short* __restrict__ Ml) {
    size_t i0 = ((size_t)blockIdx.x * 256 + threadIdx.x) * 8;
    size_t dst = (i0 < (size_t)NN * NN) ? i0 : i0 + (size_t)NN * NN;
    unsigned short h8[8], l8[8];
    #pragma unroll
    for (int j = 0; j < 8; j++) split_bf(temp[i0 + j], h8[j], l8[j]);
    *(uint4*)(Mh + dst) = *(uint4*)h8;
    *(uint4*)(Ml + dst) = *(uint4*)l8;
}

__global__ void k_featd_h(const float* __restrict__ h, float* __restrict__ featd) {
    size_t idx = (size_t)blockIdx.x * 256 + threadIdx.x;
    size_t row = idx >> 6; int c = (int)(idx & 63);
    featd[row * DIN + c] = h[idx];
}

__global__ __launch_bounds__(256) void k_z(
        const float* __restrict__ featd, const float* __restrict__ W_diff,
        const float* __restrict__ b_diff, float* __restrict__ z) {
    int row0 = blockIdx.x * 4;
    __shared__ float sF[4 * DIN];
    int tid = threadIdx.x;
    for (int i = tid; i < 4 * DIN / 4; i += 256)
        *(float4*)&sF[i * 4] = *(const float4*)&featd[(size_t)row0 * DIN + (size_t)i * 4];
    __syncthreads();
    int lr = tid >> 6, ch = tid & 63;
    const float* f = &sF[lr * DIN];
    float acc = b_diff[ch];
    for (int k = 0; k < DIN; k++) acc += f[k] * W_diff[k * HH + ch];
    z[(size_t)(row0 + lr) * HH + ch] = acc;
}

__global__ void k_dec(const float* __restrict__ z, const float* __restrict__ W_dec,
                      const float* __restrict__ b_dec, float* __restrict__ out) {
    size_t idx = (size_t)blockIdx.x * 256 + threadIdx.x;
    size_t row = idx / ODIM; int o = (int)(idx % ODIM);
    const float* zr = z + row * HH;
    float acc = b_dec[o];
    for (int k = 0; k < HH; k++) acc += zr[k] * W_dec[k * ODIM + o];
    int b = (int)(row >> 10), n = (int)(row & 1023);
    int t = o >> 3, f = o & 7;
    out[(((size_t)b * TT + t) * NN + n) * FF + f] = acc;
}

extern "C" void kernel_launch(void* const* d_in, const int* in_sizes, int n_in,
                              void* d_out, int out_size, void* d_ws, size_t ws_size,
                              hipStream_t stream) {
    const float* x      = (const float*)d_in[0];
    const int*   eiraw  = (const int*)  d_in[1];
    const float* ew     = (const float*)d_in[2];
    const float* adj    = (const float*)d_in[3];
    const float* W_enc  = (const float*)d_in[4];
    const float* b_enc  = (const float*)d_in[5];
    const float* emb    = (const float*)d_in[6];
    const float* W_r    = (const float*)d_in[7];
    const float* b_r    = (const float*)d_in[8];
    const float* W_u    = (const float*)d_in[9];
    const float* b_u    = (const float*)d_in[10];
    const float* W_c    = (const float*)d_in[11];
    const float* b_c    = (const float*)d_in[12];
    const float* W_diff = (const float*)d_in[13];
    const float* b_diff = (const float*)d_in[14];
    const float* W_dec  = (const float*)d_in[15];
    const float* b_dec  = (const float*)d_in[16];

    // ---- workspace: 60.0 MiB ----
    unsigned short* Mfh = (unsigned short*)d_ws;          // frag hi 8 MiB
    unsigned short* Mfl = Mfh + (size_t)4096 * NN;        // frag lo 8 MiB
    unsigned short* XTh = Mfl + (size_t)4096 * NN;        // 4 MiB
    unsigned short* XTl = XTh + (size_t)BB * 128 * NN;    // 4 MiB
    float* feats = (float*)(XTl + (size_t)BB * 128 * NN); // 32 MiB
    float* h     = feats + (size_t)BB * NN * FS;          // 4 MiB
    // overlays inside feats:
    unsigned short* Mph = (unsigned short*)feats;         // plain hi 8 MiB
    unsigned short* Mpl = Mph + (size_t)4096 * NN;        // plain lo 8 MiB
    float* sptmp = feats + (size_t)4 * 1024 * 1024;       // 8 MiB
    float* rinv  = feats + (size_t)6 * 1024 * 1024;
    float* cinv  = rinv + NN;
    int*   eifl  = (int*)(cinv + NN);
    int*   ei32  = eifl + 4;
    float* degd  = (float*)(ei32 + 2 * EE);
    float* degs  = degd + NN;
    float* featd = feats;
    float* z     = h;

    hipMemsetAsync(h, 0, (size_t)BB * NN * HH * 4, stream);

    // ---- build plain M = [Af; Af^2; Ab; Ab^2], convert to fragment-major ----
    k_rowsum<<<NN, 256, 0, stream>>>(adj, rinv);
    k_colsum<<<NN / 256, 256, 0, stream>>>(adj, cinv);
    k_prepA<<<dim3(16, 16), 256, 0, stream>>>(adj, rinv, cinv, Mph, Mpl);
    k_msq<<<dim3(16, 16, 2), 256, 0, stream>>>(Mph, Mpl);
    k_m2frag<<<2048, 256, 0, stream>>>(Mph, Mpl, Mfh, Mfl);
    hipMemsetAsync(XTh, 0, (size_t)BB * 128 * NN * 2 * 2, stream);  // XTh+XTl (h=0 at t=0)

    for (int t = 0; t < TT; t++) {
        k_encT<<<BB * 64, 128, 0, stream>>>(x, W_enc, b_enc, emb, XTh, XTl, t);
        // 4 operators x [x|h] -> feats cols g*128 + 0..127
        k_hopA<<<dim3(32, 2, 16), 256, 0, stream>>>(Mfh, Mfl, XTh, XTl, 0, feats, FS, 128, 0);
        // gates: rh -> XT h-cols, u -> XT x-cols
        k_gates<<<BB * NN / 32, 256, 0, stream>>>(feats, W_r, W_u, b_r, b_u, h, XTh, XTl);
        // 4 operators @ rh -> feats h-cols
        k_hopA<<<dim3(32, 1, 16), 256, 0, stream>>>(Mfh, Mfl, XTh, XTl, 64, feats, FS, 128, 64);
        // candidate + h update
        k_cand<<<BB * NN / 32, 256, 0, stream>>>(feats, W_c, b_c, XTh, XTl, h, XTh, XTl);
    }

    // ---- DiffConv readout ----
    k_ei_detect<<<1, 256, 0, stream>>>(eiraw, eifl);
    k_ei_norm<<<2 * EE / 256, 256, 0, stream>>>(eiraw, eifl, ei32);
    hipMemsetAsync(degd, 0, (size_t)2 * NN * 4, stream);
    hipMemsetAsync(sptmp, 0, (size_t)2 * NN * NN * 4, stream);
    k_deg<<<EE / 256, 256, 0, stream>>>(ei32, ew, degd, degs);
    k_spadd<<<EE / 256, 256, 0, stream>>>(ei32, ew, degd, degs, sptmp);
    k_spconv<<<2 * NN * NN / (256 * 8), 256, 0, stream>>>(sptmp, Mph, Mpl);
    k_msq<<<dim3(16, 16, 2), 256, 0, stream>>>(Mph, Mpl);
    k_m2frag<<<2048, 256, 0, stream>>>(Mph, Mpl, Mfh, Mfl);
    k_featd_h<<<BB * NN * HH / 256, 256, 0, stream>>>(h, featd);
    // [Sf;Sf2;Sb;Sb2] @ h (hT in XT h-cols) -> featd cols 64 + g*64
    k_hopA<<<dim3(32, 1, 16), 256, 0, stream>>>(Mfh, Mfl, XTh, XTl, 64, featd, DIN, 64, 64);
    k_z<<<BB * NN / 4, 256, 0, stream>>>(featd, W_diff, b_diff, z);
    k_dec<<<(BB * NN * ODIM) / 256, 256, 0, stream>>>(z, W_dec, b_dec, (float*)d_out);
}